// Round 8
// baseline (7192.377 us; speedup 1.0000x reference)
//
#include <hip/hip_runtime.h>
#include <hip/hip_fp16.h>

// Decoder: 2-layer LSTM (H=256), T=512, B=256, scalar output feedback.
// Round 11: NB=2 on the u8 skeleton. R7 cut streamed bytes to 624 KB/step
// (port term 13.3K cyc, ~53% of the measured 47 B/cyc per-CU ceiling);
// phases now alternate port-bound (L1) and VALU-bound. NB=2 amortizes each
// weight fetch over 2 batch elements at zero extra port cost, and the
// u8->fp16 v_perm decode is SHARED between batches (24 VALU per uint4 for
// 2 elems vs 16 for 1). grid=128, half the CUs idle -- irrelevant, the
// per-CU VMEM port is the currency (R4-proven).
//  - Keeps: u8 per-row-scale weights + bias-1152 cancellation (R7-proven),
//    uint4 loads, LICM fence, 144KB LDS cache of whh0 (forces 1 block/CU),
//    dual redundant per-wave reduces (R4-proven pattern).

namespace {

constexpr int kB = 256, kT = 512, kH = 256;
constexpr int kBW = 16;                     // big-windows of 16 k per matrix
constexpr int kLdsBW = 9;                   // whh0 bigwins in LDS (144 KB)
constexpr int kU4PerMat = kBW * 1024;       // 16384 uint4 per matrix
constexpr size_t kWsNeeded =
    3 * (size_t)kU4PerMat * 16 + 3 * 1024 * 4;  // 786432 + 12288 = 798720

typedef _Float16 h2_t __attribute__((ext_vector_type(2)));

__device__ __forceinline__ float fsig(float v) { return 1.0f / (1.0f + __expf(-v)); }

__device__ __forceinline__ float fdot2f(uint a, uint b, float acc) {
#if __has_builtin(__builtin_amdgcn_fdot2)
  return __builtin_amdgcn_fdot2(__builtin_bit_cast(h2_t, a),
                                __builtin_bit_cast(h2_t, b), acc, false);
#else
  float2 fa = __half22float2(__builtin_bit_cast(__half2, a));
  float2 fb = __half22float2(__builtin_bit_cast(__half2, b));
  return fmaf(fa.y, fb.y, fmaf(fa.x, fb.x, acc));
#endif
}

// Expand byte-pair of q into half2 {1024+b_lo, 1024+b_hi} (exact in fp16).
__device__ __forceinline__ uint q2h_lo(uint q) {
#if __has_builtin(__builtin_amdgcn_perm)
  return __builtin_amdgcn_perm(0x64646464u, q, 0x04010400u);  // {b0,64,b1,64}
#else
  return 0x64006400u | (q & 0xFFu) | ((q & 0xFF00u) << 8);
#endif
}
__device__ __forceinline__ uint q2h_hi(uint q) {
#if __has_builtin(__builtin_amdgcn_perm)
  return __builtin_amdgcn_perm(0x64646464u, q, 0x04030402u);  // {b2,64,b3,64}
#else
  return 0x64006400u | ((q >> 16) & 0xFFu) | ((q >> 8) & 0xFF0000u);
#endif
}

// 16-wide u8 dot vs fp16 h for TWO batch elements, sharing the q decode.
// DA += sum (1024+q_k)*hA_k ; DB += sum (1024+q_k)*hB_k.
__device__ __forceinline__ void dot16x2(uint4 q, uint4 a0, uint4 a1,
                                        uint4 b0, uint4 b1, float& DA,
                                        float& DB) {
  uint e;
  e = q2h_lo(q.x); DA = fdot2f(e, a0.x, DA); DB = fdot2f(e, b0.x, DB);
  e = q2h_hi(q.x); DA = fdot2f(e, a0.y, DA); DB = fdot2f(e, b0.y, DB);
  e = q2h_lo(q.y); DA = fdot2f(e, a0.z, DA); DB = fdot2f(e, b0.z, DB);
  e = q2h_hi(q.y); DA = fdot2f(e, a0.w, DA); DB = fdot2f(e, b0.w, DB);
  e = q2h_lo(q.z); DA = fdot2f(e, a1.x, DA); DB = fdot2f(e, b1.x, DB);
  e = q2h_hi(q.z); DA = fdot2f(e, a1.y, DA); DB = fdot2f(e, b1.y, DB);
  e = q2h_lo(q.w); DA = fdot2f(e, a1.z, DA); DB = fdot2f(e, b1.z, DB);
  e = q2h_hi(q.w); DA = fdot2f(e, a1.w, DA); DB = fdot2f(e, b1.w, DB);
}

// One wave-row per matrix row: per-row absmax -> scale, quantize 256 w to u8.
// dst layout (u32 view, per matrix): [bw(16)][j(1024)][c(4)], bytes of
// k = 16*bw + 4*c .. +3. Main loop reads uint4 tile[bw*1024 + j].
__global__ __launch_bounds__(64) void pack_q(const float* __restrict__ s0,
                                             const float* __restrict__ s1,
                                             const float* __restrict__ s2,
                                             uint* __restrict__ dst,
                                             float* __restrict__ scl) {
  int r = blockIdx.x;                 // 0..3071
  int mat = r >> 10, j = r & 1023;
  int ln = threadIdx.x;               // 0..63, covers k = 4*ln..4*ln+3
  const float* src = (mat == 0 ? s0 : (mat == 1 ? s1 : s2)) + j * 256 + ln * 4;
  float4 v = *(const float4*)src;
  float m = fmaxf(fmaxf(fabsf(v.x), fabsf(v.y)), fmaxf(fabsf(v.z), fabsf(v.w)));
#pragma unroll
  for (int off = 32; off > 0; off >>= 1) m = fmaxf(m, __shfl_xor(m, off));
  float rcp = (m > 0.f) ? 127.0f / m : 0.f;
  uint q0 = (uint)(__float2int_rn(v.x * rcp) + 128);
  uint q1 = (uint)(__float2int_rn(v.y * rcp) + 128);
  uint q2 = (uint)(__float2int_rn(v.z * rcp) + 128);
  uint q3 = (uint)(__float2int_rn(v.w * rcp) + 128);
  uint packed = q0 | (q1 << 8) | (q2 << 16) | (q3 << 24);
  dst[mat * 65536 + (ln >> 2) * 4096 + j * 4 + (ln & 3)] = packed;
  if (ln == 0) scl[mat * 1024 + j] = m * (1.0f / 127.0f);
}

__global__ __launch_bounds__(1024) void decoder_q8nb2(
    const float* __restrict__ seq, const float* __restrict__ z,
    const float* __restrict__ wih0, const float* __restrict__ bih0,
    const float* __restrict__ bhh0, const float* __restrict__ bih1,
    const float* __restrict__ bhh1, const float* __restrict__ wout,
    const float* __restrict__ bout, const uint4* __restrict__ w0,
    const uint4* __restrict__ w1i, const uint4* __restrict__ w1h,
    const float* __restrict__ scl, float* __restrict__ loss_out) {
  extern __shared__ uint4 lw[];                   // kLdsBW bigwins of whh0
  __shared__ alignas(16) _Float16 h0h[2][kH];     // hidden, layer 0 (fp16)
  __shared__ alignas(16) _Float16 h1h[2][kH];     // hidden, layer 1 (fp16)
  __shared__ float g4[2][1024];
  __shared__ float spred[2][kH];

  const int tid = threadIdx.x;                    // gate row j
  const int b0 = blockIdx.x * 2;                  // batch pair
  const int m = tid >> 8, hr = tid & 255;         // cell role (tid<512)

  // Stage whh0 bigwins 0..kLdsBW-1 into LDS (coalesced 16B copies).
#pragma unroll
  for (int i = 0; i < kLdsBW; ++i) lw[i * 1024 + tid] = w0[i * 1024 + tid];

  float c0 = 0.f, c1 = 0.f, woutr = 0.f;
  if (tid < 512) {
    float zv = z[(size_t)(b0 + m) * kH + hr];
    h0h[m][hr] = (_Float16)zv;
    h1h[m][hr] = (_Float16)zv;
    c0 = zv;
    c1 = zv;
    woutr = wout[hr];
  }
  const float wih0_j = wih0[tid];
  const float bias0 = bih0[tid] + bhh0[tid];
  const float bias1 = bih1[tid] + bhh1[tid];
  const float s0j = scl[tid];
  const float s1ij = scl[1024 + tid];
  const float s1hj = scl[2048 + tid];
  const float bo = bout[0];
  const bool isG = (tid >= 512) && (tid < 768);   // wave-uniform (waves 8..11)
  float xsA = 0.f, xsB = 0.f, lacc = 0.f;

  const uint4* wp0 = w0 + tid;
  const uint4* wpA = w1i + tid;
  const uint4* wpB = w1h + tid;
  const uint4* lwp = lw + tid;
  const uint4* h0uA = (const uint4*)h0h[0];       // 2 uint4 per bigwin
  const uint4* h0uB = (const uint4*)h0h[1];
  const uint4* h1uA = (const uint4*)h1h[0];
  const uint4* h1uB = (const uint4*)h1h[1];
  const uint2* h0d = (const uint2*)h0h;           // [2][64] uint2 rows
  const uint2* h1d = (const uint2*)h1h;
  const uint ONES = 0x3C003C00u;                  // half2 {1.0, 1.0}
  __syncthreads();

  // Initial per-batch sums of h (h0==h1==z), wave-redundant dual reduce.
  float sh0A, sh0B, sh1A, sh1B;
  {
    int ln = tid & 63;
    uint2 uA = h0d[ln];
    uint2 uB = h0d[64 + ln];
    float pA = fdot2f(uA.y, ONES, fdot2f(uA.x, ONES, 0.f));
    float pB = fdot2f(uB.y, ONES, fdot2f(uB.x, ONES, 0.f));
#pragma unroll
    for (int off = 32; off > 0; off >>= 1) {
      pA += __shfl_xor(pA, off);
      pB += __shfl_xor(pB, off);
    }
    sh0A = pA; sh1A = pA;
    sh0B = pB; sh1B = pB;
  }

  for (int t = 0; t < kT; ++t) {
    // LICM fence (round-5 post-mortem: hoist->spill->scratch-bound).
    asm volatile("" ::: "memory");

    // ---- layer 0: D = sum (1024+q)*h0 over 256 k, both batches ----
    float D0A = 0.f, D0B = 0.f;
#pragma unroll
    for (int bw = 0; bw < kLdsBW; ++bw)           // LDS-cached bigwins
      dot16x2(lwp[bw << 10], h0uA[2 * bw], h0uA[2 * bw + 1], h0uB[2 * bw],
              h0uB[2 * bw + 1], D0A, D0B);
#pragma unroll 4
    for (int bw = kLdsBW; bw < kBW; ++bw)         // L2-streamed bigwins
      dot16x2(wp0[(size_t)bw << 10], h0uA[2 * bw], h0uA[2 * bw + 1],
              h0uB[2 * bw], h0uB[2 * bw + 1], D0A, D0B);
    float a0A = fmaf(xsA, wih0_j, bias0) + s0j * fmaf(-1152.f, sh0A, D0A);
    float a0B = fmaf(xsB, wih0_j, bias0) + s0j * fmaf(-1152.f, sh0B, D0B);
    if (isG) { g4[0][tid] = tanhf(a0A); g4[1][tid] = tanhf(a0B); }
    else     { g4[0][tid] = fsig(a0A);  g4[1][tid] = fsig(a0B); }
    __syncthreads();
    if (tid < 512) {
      float gi = g4[m][hr];
      float gf = g4[m][hr + 256];
      float gg = g4[m][hr + 512];
      float go = g4[m][hr + 768];
      c0 = fmaf(gf, c0, gi * gg);
      h0h[m][hr] = (_Float16)(go * tanhf(c0));
    }
    __syncthreads();

    // new per-batch sums of h0 (for this step's L1 and next step's L0)
    {
      int ln = tid & 63;
      uint2 uA = h0d[ln];
      uint2 uB = h0d[64 + ln];
      float pA = fdot2f(uA.y, ONES, fdot2f(uA.x, ONES, 0.f));
      float pB = fdot2f(uB.y, ONES, fdot2f(uB.x, ONES, 0.f));
#pragma unroll
      for (int off = 32; off > 0; off >>= 1) {
        pA += __shfl_xor(pA, off);
        pB += __shfl_xor(pB, off);
      }
      sh0A = pA;
      sh0B = pB;
    }

    // ---- layer 1: D1i vs h0new, D1h vs h1old, both batches ----
    float DiA = 0.f, DiB = 0.f, DhA = 0.f, DhB = 0.f;
#pragma unroll 2
    for (int bw = 0; bw < kBW; ++bw) {
      uint4 qA = wpA[(size_t)bw << 10];
      uint4 qB = wpB[(size_t)bw << 10];
      dot16x2(qA, h0uA[2 * bw], h0uA[2 * bw + 1], h0uB[2 * bw],
              h0uB[2 * bw + 1], DiA, DiB);
      dot16x2(qB, h1uA[2 * bw], h1uA[2 * bw + 1], h1uB[2 * bw],
              h1uB[2 * bw + 1], DhA, DhB);
    }
    float a1A = bias1 + s1ij * fmaf(-1152.f, sh0A, DiA) +
                s1hj * fmaf(-1152.f, sh1A, DhA);
    float a1B = bias1 + s1ij * fmaf(-1152.f, sh0B, DiB) +
                s1hj * fmaf(-1152.f, sh1B, DhB);
    if (isG) { g4[0][tid] = tanhf(a1A); g4[1][tid] = tanhf(a1B); }
    else     { g4[0][tid] = fsig(a1A);  g4[1][tid] = fsig(a1B); }
    __syncthreads();
    if (tid < 512) {
      float gi = g4[m][hr];
      float gf = g4[m][hr + 256];
      float gg = g4[m][hr + 512];
      float go = g4[m][hr + 768];
      c1 = fmaf(gf, c1, gi * gg);
      float hn = go * tanhf(c1);                  // fp32, pre-rounding
      h1h[m][hr] = (_Float16)hn;
      spred[m][hr] = hn * woutr;                  // pred path stays fp32
    }
    __syncthreads();

    // ---- dual pred reduce (redundant per wave) + new sums of h1 ----
    {
      int ln = tid & 63;
      float vA = spred[0][ln] + spred[0][ln + 64] + spred[0][ln + 128] +
                 spred[0][ln + 192];
      float vB = spred[1][ln] + spred[1][ln + 64] + spred[1][ln + 128] +
                 spred[1][ln + 192];
#pragma unroll
      for (int off = 32; off > 0; off >>= 1) {
        vA += __shfl_down(vA, off);
        vB += __shfl_down(vB, off);
      }
      float predA = __shfl(vA, 0) + bo;           // broadcast within wave
      float predB = __shfl(vB, 0) + bo;
      xsA = predA;                                // feedback for next step
      xsB = predB;
      if (tid == 0) {
        float dA = seq[(size_t)b0 * kT + t] - predA;
        float dB = seq[(size_t)(b0 + 1) * kT + t] - predB;
        lacc = fmaf(dA, dA, lacc);
        lacc = fmaf(dB, dB, lacc);
      }
      uint2 uA = h1d[ln];
      uint2 uB = h1d[64 + ln];
      float pA = fdot2f(uA.y, ONES, fdot2f(uA.x, ONES, 0.f));
      float pB = fdot2f(uB.y, ONES, fdot2f(uB.x, ONES, 0.f));
#pragma unroll
      for (int off = 32; off > 0; off >>= 1) {
        pA += __shfl_xor(pA, off);
        pB += __shfl_xor(pB, off);
      }
      sh1A = pA;
      sh1B = pB;
    }
    // no extra barrier: next writer of spred/h passes 2+ barriers first
  }

  if (tid == 0) atomicAdd(loss_out, lacc * (1.0f / ((float)kB * (float)kT)));
}

// ---------------- fallback (reads d_in directly, fp32) ---------------------
__global__ __launch_bounds__(1024) void decoder_fallback(
    const float* __restrict__ seq, const float* __restrict__ z,
    const float* __restrict__ wih0, const float* __restrict__ bih0,
    const float* __restrict__ bhh0, const float* __restrict__ whh0,
    const float* __restrict__ wih1, const float* __restrict__ whh1,
    const float* __restrict__ bih1, const float* __restrict__ bhh1,
    const float* __restrict__ wout, const float* __restrict__ bout,
    float* __restrict__ loss_out) {
  __shared__ float h0s[kH], h1s[kH], g4[1024];
  __shared__ float xs_s;
  const int tid = threadIdx.x;
  const int b = blockIdx.x;
  float c0r = 0.f, c1r = 0.f;
  if (tid < kH) {
    float zv = z[b * kH + tid];
    h0s[tid] = zv; h1s[tid] = zv; c0r = zv; c1r = zv;
  }
  if (tid == 0) xs_s = 0.f;
  const float wih0_j = wih0[tid];
  const float bias0_j = bih0[tid] + bhh0[tid];
  const float bias1_j = bih1[tid] + bhh1[tid];
  const float wout_r = (tid < kH) ? wout[tid] : 0.f;
  const float bo = bout[0];
  float lacc = 0.f;
  __syncthreads();
  for (int t = 0; t < kT; ++t) {
    float a0 = fmaf(xs_s, wih0_j, bias0_j);
    for (int k = 0; k < kH; ++k) a0 = fmaf(whh0[tid * kH + k], h0s[k], a0);
    g4[tid] = a0;
    __syncthreads();
    if (tid < kH) {
      float ig = fsig(g4[tid]), fg = fsig(g4[tid + 256]);
      float gg = tanhf(g4[tid + 512]), og = fsig(g4[tid + 768]);
      c0r = fmaf(fg, c0r, ig * gg);
      h0s[tid] = og * tanhf(c0r);
    }
    __syncthreads();
    float a1 = bias1_j;
    for (int k = 0; k < kH; ++k) a1 = fmaf(wih1[tid * kH + k], h0s[k], a1);
    for (int k = 0; k < kH; ++k) a1 = fmaf(whh1[tid * kH + k], h1s[k], a1);
    g4[tid] = a1;
    __syncthreads();
    if (tid < kH) {
      float ig = fsig(g4[tid]), fg = fsig(g4[tid + 256]);
      float gg = tanhf(g4[tid + 512]), og = fsig(g4[tid + 768]);
      c1r = fmaf(fg, c1r, ig * gg);
      float h1 = og * tanhf(c1r);
      h1s[tid] = h1;
      g4[tid] = h1 * wout_r;
    }
    __syncthreads();
    if (tid < 64) {
      float v = g4[tid] + g4[tid + 64] + g4[tid + 128] + g4[tid + 192];
#pragma unroll
      for (int off = 32; off > 0; off >>= 1) v += __shfl_down(v, off);
      if (tid == 0) {
        float pred = v + bo;
        float d = seq[b * kT + t] - pred;
        lacc = fmaf(d, d, lacc);
        xs_s = pred;
      }
    }
    __syncthreads();
  }
  if (tid == 0) atomicAdd(loss_out, lacc * (1.0f / (float)(kB * kT)));
}

}  // namespace

extern "C" void kernel_launch(void* const* d_in, const int* in_sizes, int n_in,
                              void* d_out, int out_size, void* d_ws, size_t ws_size,
                              hipStream_t stream) {
  const float* seq = (const float*)d_in[0];
  const float* z = (const float*)d_in[1];
  const float* wih0 = (const float*)d_in[3];
  const float* whh0 = (const float*)d_in[4];
  const float* bih0 = (const float*)d_in[5];
  const float* bhh0 = (const float*)d_in[6];
  const float* wih1 = (const float*)d_in[7];
  const float* whh1 = (const float*)d_in[8];
  const float* bih1 = (const float*)d_in[9];
  const float* bhh1 = (const float*)d_in[10];
  const float* wout = (const float*)d_in[11];
  const float* bout = (const float*)d_in[12];
  float* out = (float*)d_out;

  hipMemsetAsync(out, 0, sizeof(float), stream);

  if (ws_size >= kWsNeeded) {
    uint* wq = (uint*)d_ws;                 // [3][65536] u32 of u8 weights
    float* scl = (float*)(wq + 3 * 65536);  // [3][1024] per-row scales
    pack_q<<<3072, 64, 0, stream>>>(whh0, wih1, whh1, wq, scl);
    // 144KB dynamic LDS cache forces 1 block/CU; 128 blocks spread over
    // 128 distinct CUs, each serving a batch pair from one weight stream.
    const uint4* wu = (const uint4*)wq;
    decoder_q8nb2<<<kB / 2, 1024, kLdsBW * 1024 * (int)sizeof(uint4), stream>>>(
        seq, z, wih0, bih0, bhh0, bih1, bhh1, wout, bout, wu,
        wu + kU4PerMat, wu + 2 * kU4PerMat, scl, out);
  } else {
    decoder_fallback<<<kB, 1024, 0, stream>>>(seq, z, wih0, bih0, bhh0, whh0,
                                              wih1, whh1, bih1, bhh1, wout, bout,
                                              out);
  }
}

// Round 9
// 3227.831 us; speedup vs baseline: 2.2282x; 2.2282x over previous
//
#include <hip/hip_runtime.h>
#include <hip/hip_fp16.h>

// Decoder: 2-layer LSTM (H=256), T=512, B=256, scalar output feedback.
// Round 12: signed-i8 everywhere on the dot path (weights AND hidden state),
// v_dot4_i32_i8 (sdot4) inner product. R8 post-mortem: NB=2 regressed (dual
// fdot2 chains + doubled h-broadcasts grew VALU faster than port shrank);
// back to R7's NB=1 skeleton. R7 balance: port 13.3K cyc, VALU ~16.8K cyc.
//  - h quantized to i8 per step (scale fixed 1/127: post-step h in (-1,1);
//    initial h=z uses a per-block dynamic scale from one init max-reduce).
//  - sdot4: 4 VALU per 16 weights vs 16 (perm+fdot2). Dot path 768->192
//    instrs; h LDS reads halve.
//  - Symmetric signed quant kills the -1152*sum_h correction: all three
//    per-step sum_h reduce phases deleted.
//  - Pred/loss path fp32 from pre-quantization h (unchanged).
//  - Keeps: uint4 weight loads, LICM fence, 144KB LDS whh0 cache (forces
//    1 block/CU), redundant per-wave pred reduce, grid=256.

namespace {

constexpr int kB = 256, kT = 512, kH = 256;
constexpr int kBW = 16;                     // big-windows of 16 k per matrix
constexpr int kLdsBW = 9;                   // whh0 bigwins in LDS (144 KB)
constexpr int kU4PerMat = kBW * 1024;       // 16384 uint4 per matrix
constexpr size_t kWsNeeded =
    3 * (size_t)kU4PerMat * 16 + 3 * 1024 * 4;  // 786432 + 12288 = 798720

__device__ __forceinline__ float fsig(float v) { return 1.0f / (1.0f + __expf(-v)); }

// 4-wide signed i8 dot-accumulate (i32).
__device__ __forceinline__ int sdot4i(uint a, uint b, int c) {
#if __has_builtin(__builtin_amdgcn_sdot4)
  return __builtin_amdgcn_sdot4((int)a, (int)b, c, false);
#else
#pragma unroll
  for (int i = 0; i < 4; ++i)
    c += (int)(char)(a >> (8 * i)) * (int)(char)(b >> (8 * i));
  return c;
#endif
}

// 16-wide i8 dot: D += sum_k qw_k * qh_k over one bigwin.
__device__ __forceinline__ int dot16i(uint4 w, uint4 h, int D) {
  D = sdot4i(w.x, h.x, D);
  D = sdot4i(w.y, h.y, D);
  D = sdot4i(w.z, h.z, D);
  D = sdot4i(w.w, h.w, D);
  return D;
}

// One wave-row per matrix row: per-row absmax -> scale, quantize to SIGNED i8.
// dst layout (u32 view, per matrix): [bw(16)][j(1024)][c(4)], bytes of
// k = 16*bw + 4*c .. +3. Main loop reads uint4 tile[bw*1024 + j].
__global__ __launch_bounds__(64) void pack_q(const float* __restrict__ s0,
                                             const float* __restrict__ s1,
                                             const float* __restrict__ s2,
                                             uint* __restrict__ dst,
                                             float* __restrict__ scl) {
  int r = blockIdx.x;                 // 0..3071
  int mat = r >> 10, j = r & 1023;
  int ln = threadIdx.x;               // 0..63, covers k = 4*ln..4*ln+3
  const float* src = (mat == 0 ? s0 : (mat == 1 ? s1 : s2)) + j * 256 + ln * 4;
  float4 v = *(const float4*)src;
  float m = fmaxf(fmaxf(fabsf(v.x), fabsf(v.y)), fmaxf(fabsf(v.z), fabsf(v.w)));
#pragma unroll
  for (int off = 32; off > 0; off >>= 1) m = fmaxf(m, __shfl_xor(m, off));
  float rcp = (m > 0.f) ? 127.0f / m : 0.f;
  int q0 = __float2int_rn(v.x * rcp);
  int q1 = __float2int_rn(v.y * rcp);
  int q2 = __float2int_rn(v.z * rcp);
  int q3 = __float2int_rn(v.w * rcp);
  uint packed = (uint)(q0 & 0xFF) | ((uint)(q1 & 0xFF) << 8) |
                ((uint)(q2 & 0xFF) << 16) | ((uint)(q3 & 0xFF) << 24);
  dst[mat * 65536 + (ln >> 2) * 4096 + j * 4 + (ln & 3)] = packed;
  if (ln == 0) scl[mat * 1024 + j] = m * (1.0f / 127.0f);
}

__global__ __launch_bounds__(1024) void decoder_i8(
    const float* __restrict__ seq, const float* __restrict__ z,
    const float* __restrict__ wih0, const float* __restrict__ bih0,
    const float* __restrict__ bhh0, const float* __restrict__ bih1,
    const float* __restrict__ bhh1, const float* __restrict__ wout,
    const float* __restrict__ bout, const uint4* __restrict__ w0,
    const uint4* __restrict__ w1i, const uint4* __restrict__ w1h,
    const float* __restrict__ scl, float* __restrict__ loss_out) {
  extern __shared__ uint4 lw[];                   // kLdsBW bigwins of whh0
  __shared__ alignas(16) uint h0q[64];            // 256 x i8 hidden, layer 0
  __shared__ alignas(16) uint h1q[64];            // 256 x i8 hidden, layer 1
  __shared__ float g4[1024];
  __shared__ float spred[kH];

  const int tid = threadIdx.x;                    // gate row j
  const int b = blockIdx.x;                       // batch element

  // Stage whh0 bigwins 0..kLdsBW-1 into LDS (coalesced 16B copies).
#pragma unroll
  for (int i = 0; i < kLdsBW; ++i) lw[i * 1024 + tid] = w0[i * 1024 + tid];

  float c0 = 0.f, c1 = 0.f, woutr = 0.f, zv = 0.f;
  if (tid < kH) {
    zv = z[(size_t)b * kH + tid];
    c0 = zv;
    c1 = zv;
    woutr = wout[tid];
    spred[tid] = fabsf(zv);                       // scratch for init max
  }
  const float wih0_j = wih0[tid];
  const float bias0 = bih0[tid] + bhh0[tid];
  const float bias1 = bih1[tid] + bhh1[tid];
  const float s0j = scl[tid];
  const float s1ij = scl[1024 + tid];
  const float s1hj = scl[2048 + tid];
  const float bo = bout[0];
  const bool isG = (tid >= 512) && (tid < 768);   // wave-uniform (waves 8..11)
  const float r127 = 1.0f / 127.0f;
  float xsv = 0.f, lacc = 0.f;
  __syncthreads();

  // Per-block max|z| (wave-redundant), init scale, quantize z into h0q/h1q.
  float s_init;
  {
    int ln = tid & 63;
    float mm = fmaxf(fmaxf(spred[ln], spred[ln + 64]),
                     fmaxf(spred[ln + 128], spred[ln + 192]));
#pragma unroll
    for (int off = 32; off > 0; off >>= 1) mm = fmaxf(mm, __shfl_xor(mm, off));
    float m = fmaxf(mm, 1e-20f);
    s_init = m * r127;                            // qh = z / s_init
    if (tid < kH) {
      int q = __float2int_rn(zv * (127.0f / m));
      q = max(-127, min(127, q));
      ((char*)h0q)[tid] = (char)q;
      ((char*)h1q)[tid] = (char)q;
    }
  }

  const uint4* wp0 = w0 + tid;
  const uint4* wpA = w1i + tid;
  const uint4* wpB = w1h + tid;
  const uint4* lwp = lw + tid;
  const uint4* h0v = (const uint4*)h0q;           // 1 uint4 (16 i8) per bigwin
  const uint4* h1v = (const uint4*)h1q;
  __syncthreads();

  for (int t = 0; t < kT; ++t) {
    // LICM fence (round-5 post-mortem: hoist->spill->scratch-bound).
    asm volatile("" ::: "memory");
    const float hs_old = (t == 0) ? s_init : r127;  // scale of h written t-1

    // ---- layer 0: D0 = sum qw*qh0 over 256 k (i32 exact) ----
    int D0 = 0;
#pragma unroll
    for (int bw = 0; bw < kLdsBW; ++bw)           // LDS-cached bigwins
      D0 = dot16i(lwp[bw << 10], h0v[bw], D0);
#pragma unroll 4
    for (int bw = kLdsBW; bw < kBW; ++bw)         // L2-streamed bigwins
      D0 = dot16i(wp0[(size_t)bw << 10], h0v[bw], D0);
    float a0 = fmaf(xsv, wih0_j, bias0) + s0j * hs_old * (float)D0;
    g4[tid] = isG ? tanhf(a0) : fsig(a0);
    __syncthreads();
    if (tid < kH) {
      float gi = g4[tid];
      float gf = g4[tid + 256];
      float gg = g4[tid + 512];
      float go = g4[tid + 768];
      c0 = fmaf(gf, c0, gi * gg);
      float hn = go * tanhf(c0);                  // in (-1,1)
      int q = __float2int_rn(hn * 127.0f);
      ((char*)h0q)[tid] = (char)q;                // scale 1/127
    }
    __syncthreads();

    // ---- layer 1: Di vs h0new (1/127), Dh vs h1old (hs_old) ----
    int Di = 0, Dh = 0;
#pragma unroll 2
    for (int bw = 0; bw < kBW; ++bw) {
      uint4 qA = wpA[(size_t)bw << 10];
      uint4 qB = wpB[(size_t)bw << 10];
      Di = dot16i(qA, h0v[bw], Di);
      Dh = dot16i(qB, h1v[bw], Dh);
    }
    float a1 = bias1 + s1ij * r127 * (float)Di + s1hj * hs_old * (float)Dh;
    g4[tid] = isG ? tanhf(a1) : fsig(a1);
    __syncthreads();
    if (tid < kH) {
      float gi = g4[tid];
      float gf = g4[tid + 256];
      float gg = g4[tid + 512];
      float go = g4[tid + 768];
      c1 = fmaf(gf, c1, gi * gg);
      float hn = go * tanhf(c1);                  // fp32, pre-quantization
      int q = __float2int_rn(hn * 127.0f);
      ((char*)h1q)[tid] = (char)q;                // scale 1/127
      spred[tid] = hn * woutr;                    // pred path stays fp32
    }
    __syncthreads();

    // ---- redundant per-wave pred reduce: pred in-register in every wave ----
    {
      int ln = tid & 63;
      float v = spred[ln] + spred[ln + 64] + spred[ln + 128] + spred[ln + 192];
#pragma unroll
      for (int off = 32; off > 0; off >>= 1) v += __shfl_down(v, off);
      float pred = __shfl(v, 0) + bo;             // broadcast within wave
      xsv = pred;                                 // feedback for next step
      if (tid == 0) {
        float d = seq[(size_t)b * kT + t] - pred;
        lacc = fmaf(d, d, lacc);
      }
    }
    // no barrier needed: next writer of spred/h passes 2+ barriers first
  }

  if (tid == 0) atomicAdd(loss_out, lacc * (1.0f / ((float)kB * (float)kT)));
}

// ---------------- fallback (reads d_in directly, fp32) ---------------------
__global__ __launch_bounds__(1024) void decoder_fallback(
    const float* __restrict__ seq, const float* __restrict__ z,
    const float* __restrict__ wih0, const float* __restrict__ bih0,
    const float* __restrict__ bhh0, const float* __restrict__ whh0,
    const float* __restrict__ wih1, const float* __restrict__ whh1,
    const float* __restrict__ bih1, const float* __restrict__ bhh1,
    const float* __restrict__ wout, const float* __restrict__ bout,
    float* __restrict__ loss_out) {
  __shared__ float h0s[kH], h1s[kH], g4[1024];
  __shared__ float xs_s;
  const int tid = threadIdx.x;
  const int b = blockIdx.x;
  float c0r = 0.f, c1r = 0.f;
  if (tid < kH) {
    float zv = z[b * kH + tid];
    h0s[tid] = zv; h1s[tid] = zv; c0r = zv; c1r = zv;
  }
  if (tid == 0) xs_s = 0.f;
  const float wih0_j = wih0[tid];
  const float bias0_j = bih0[tid] + bhh0[tid];
  const float bias1_j = bih1[tid] + bhh1[tid];
  const float wout_r = (tid < kH) ? wout[tid] : 0.f;
  const float bo = bout[0];
  float lacc = 0.f;
  __syncthreads();
  for (int t = 0; t < kT; ++t) {
    float a0 = fmaf(xs_s, wih0_j, bias0_j);
    for (int k = 0; k < kH; ++k) a0 = fmaf(whh0[tid * kH + k], h0s[k], a0);
    g4[tid] = a0;
    __syncthreads();
    if (tid < kH) {
      float ig = fsig(g4[tid]), fg = fsig(g4[tid + 256]);
      float gg = tanhf(g4[tid + 512]), og = fsig(g4[tid + 768]);
      c0r = fmaf(fg, c0r, ig * gg);
      h0s[tid] = og * tanhf(c0r);
    }
    __syncthreads();
    float a1 = bias1_j;
    for (int k = 0; k < kH; ++k) a1 = fmaf(wih1[tid * kH + k], h0s[k], a1);
    for (int k = 0; k < kH; ++k) a1 = fmaf(whh1[tid * kH + k], h1s[k], a1);
    g4[tid] = a1;
    __syncthreads();
    if (tid < kH) {
      float ig = fsig(g4[tid]), fg = fsig(g4[tid + 256]);
      float gg = tanhf(g4[tid + 512]), og = fsig(g4[tid + 768]);
      c1r = fmaf(fg, c1r, ig * gg);
      float h1 = og * tanhf(c1r);
      h1s[tid] = h1;
      g4[tid] = h1 * wout_r;
    }
    __syncthreads();
    if (tid < 64) {
      float v = g4[tid] + g4[tid + 64] + g4[tid + 128] + g4[tid + 192];
#pragma unroll
      for (int off = 32; off > 0; off >>= 1) v += __shfl_down(v, off);
      if (tid == 0) {
        float pred = v + bo;
        float d = seq[b * kT + t] - pred;
        lacc = fmaf(d, d, lacc);
        xs_s = pred;
      }
    }
    __syncthreads();
  }
  if (tid == 0) atomicAdd(loss_out, lacc * (1.0f / (float)(kB * kT)));
}

}  // namespace

extern "C" void kernel_launch(void* const* d_in, const int* in_sizes, int n_in,
                              void* d_out, int out_size, void* d_ws, size_t ws_size,
                              hipStream_t stream) {
  const float* seq = (const float*)d_in[0];
  const float* z = (const float*)d_in[1];
  const float* wih0 = (const float*)d_in[3];
  const float* whh0 = (const float*)d_in[4];
  const float* bih0 = (const float*)d_in[5];
  const float* bhh0 = (const float*)d_in[6];
  const float* wih1 = (const float*)d_in[7];
  const float* whh1 = (const float*)d_in[8];
  const float* bih1 = (const float*)d_in[9];
  const float* bhh1 = (const float*)d_in[10];
  const float* wout = (const float*)d_in[11];
  const float* bout = (const float*)d_in[12];
  float* out = (float*)d_out;

  hipMemsetAsync(out, 0, sizeof(float), stream);

  if (ws_size >= kWsNeeded) {
    uint* wq = (uint*)d_ws;                 // [3][65536] u32 of i8 weights
    float* scl = (float*)(wq + 3 * 65536);  // [3][1024] per-row scales
    pack_q<<<3072, 64, 0, stream>>>(whh0, wih1, whh1, wq, scl);
    // 144KB dynamic LDS weight cache also forces 1 block/CU -> 256 blocks
    // land on 256 distinct CUs (full machine).
    const uint4* wu = (const uint4*)wq;
    decoder_i8<<<kB, 1024, kLdsBW * 1024 * (int)sizeof(uint4), stream>>>(
        seq, z, wih0, bih0, bhh0, bih1, bhh1, wout, bout, wu,
        wu + kU4PerMat, wu + 2 * kU4PerMat, scl, out);
  } else {
    decoder_fallback<<<kB, 1024, 0, stream>>>(seq, z, wih0, bih0, bhh0, whh0,
                                              wih1, whh1, bih1, bhh1, wout, bout,
                                              out);
  }
}